// Round 5
// baseline (526.984 us; speedup 1.0000x reference)
//
#include <hip/hip_runtime.h>

#define NN 20000
#define NE 320000
#define NG 256
#define EB 1250  // NE / 256 exactly

// ---------------- CSR build ----------------

// grid = 2*EB: first EB blocks histogram dis dst, rest edge dst.
__global__ __launch_bounds__(256) void hist_both_kernel(
    const int* __restrict__ dis_dst, const int* __restrict__ edge_dst,
    int* __restrict__ cnt_d, int* __restrict__ cnt_e) {
  int b = blockIdx.x;
  if (b < EB) {
    int e = b * 256 + threadIdx.x;
    atomicAdd(&cnt_d[dis_dst[e]], 1);
  } else {
    int e = (b - EB) * 256 + threadIdx.x;
    atomicAdd(&cnt_e[edge_dst[e]], 1);
  }
}

// grid = 2: block 0 scans cnt_d -> rp_d, block 1 scans cnt_e -> rp_e.
__global__ __launch_bounds__(1024) void scan_both_kernel(
    const int* __restrict__ cnt_d, int* __restrict__ rp_d,
    const int* __restrict__ cnt_e, int* __restrict__ rp_e) {
  const int* counts = (blockIdx.x == 0) ? cnt_d : cnt_e;
  int* rowptr = (blockIdx.x == 0) ? rp_d : rp_e;
  __shared__ int wsum[16];
  __shared__ int carry_s;
  int t = threadIdx.x;
  int lane = t & 63;
  int w = t >> 6;
  if (t == 0) carry_s = 0;
  __syncthreads();
  for (int base = 0; base < NN; base += 1024) {
    int v = (base + t < NN) ? counts[base + t] : 0;
    int incl = v;
#pragma unroll
    for (int off = 1; off < 64; off <<= 1) {
      int g = __shfl_up(incl, off);
      if (lane >= off) incl += g;
    }
    if (lane == 63) wsum[w] = incl;
    __syncthreads();
    if (w == 0 && lane < 16) {
      int s = wsum[lane];
#pragma unroll
      for (int off = 1; off < 16; off <<= 1) {
        int g = __shfl_up(s, off);
        if (lane >= off) s += g;
      }
      wsum[lane] = s;
    }
    __syncthreads();
    int woff = (w > 0) ? wsum[w - 1] : 0;
    int carry = carry_s;
    int tot = carry + woff + incl;
    if (base + t < NN) rowptr[base + t] = tot - v;  // exclusive
    __syncthreads();
    if (t == 1023) carry_s = tot;
    __syncthreads();
  }
  if (t == 0) rowptr[NN] = carry_s;
}

// grid = 2*EB, mirrors hist_both.
__global__ __launch_bounds__(256) void scatter_both_kernel(
    const int* __restrict__ dis_idx, const int* __restrict__ edge_idx,
    const int* __restrict__ rp_d, const int* __restrict__ rp_e,
    int* __restrict__ cur_d, int* __restrict__ cur_e,
    int* __restrict__ s_d, int* __restrict__ s_e) {
  int b = blockIdx.x;
  if (b < EB) {
    int e = b * 256 + threadIdx.x;
    int d = dis_idx[NE + e];
    int pos = rp_d[d] + atomicAdd(&cur_d[d], 1);
    s_d[pos] = dis_idx[e];
  } else {
    int e = (b - EB) * 256 + threadIdx.x;
    int d = edge_idx[NE + e];
    int pos = rp_e[d] + atomicAdd(&cur_e[d], 1);
    s_e[pos] = edge_idx[e];
  }
}

// ---------------- first GEMM + attention sums ----------------

__global__ __launch_bounds__(256) void gemm_attn_kernel(
    const float* __restrict__ x, const float* __restrict__ W,
    const float* __restrict__ att_src, const float* __restrict__ att_dst,
    float* __restrict__ h, float* __restrict__ a_src, float* __restrict__ a_dst) {
  __shared__ float xs[4][64];
  __shared__ float ws[64 * 64];
  int t = threadIdx.x;
  int lr = t >> 6;
  int c = t & 63;
  int n = blockIdx.x * 4 + lr;
  const float4* W4 = (const float4*)W;
  float4* ws4 = (float4*)ws;
  for (int k = t; k < 1024; k += 256) ws4[k] = W4[k];
  xs[lr][c] = x[n * 64 + c];
  __syncthreads();
  float acc = 0.f;
#pragma unroll
  for (int k = 0; k < 64; ++k) acc = fmaf(xs[lr][k], ws[k * 64 + c], acc);
  h[n * 64 + c] = acc;
  float ts = acc * att_src[c];
  float td = acc * att_dst[c];
#pragma unroll
  for (int off = 1; off < 8; off <<= 1) {
    ts += __shfl_xor(ts, off);
    td += __shfl_xor(td, off);
  }
  if ((c & 7) == 0) {
    a_src[n * 8 + (c >> 3)] = ts;
    a_dst[n * 8 + (c >> 3)] = td;
  }
}

// ---------------- fused agg (+ optional next-conv GEMM/attn) ----------------
// One wave per dst node. lane = (half, p): handles channels {2p, 2p+1} of the
// node; half 0 processes even edges, half 1 odd edges (paired-edge float2
// gathers: one instruction fetches 2 edges x 256B). Src indices for up to 64
// edges preloaded in ONE coalesced load. Halves combined via shfl_xor(32).
template <int H, bool RELU, int HN>
__global__ __launch_bounds__(256) void agg_fused_kernel(
    const float* __restrict__ h, const float* __restrict__ a_src,
    const float* __restrict__ a_dst, const int* __restrict__ rowptr,
    const int* __restrict__ srcs, const float* __restrict__ bias,
    float* __restrict__ out, const float* __restrict__ Wn,
    const float* __restrict__ asn, const float* __restrict__ adn,
    float* __restrict__ a_src_n, float* __restrict__ a_dst_n) {
  extern __shared__ float ws[];
  int t = threadIdx.x;
  int i = blockIdx.x * 4 + (t >> 6);
  int lane = t & 63;
  int half = lane >> 5;
  int p = lane & 31;  // channel pair; channels 2p, 2p+1 (same head always)
  if (HN != 0) {
    const float4* W4 = (const float4*)Wn;
    float4* ws4 = (float4*)ws;
    for (int k = t; k < 1024; k += 256) ws4[k] = W4[k];
    __syncthreads();
  }
  const int hd = (H == 8) ? (p >> 2) : 0;
  float ad = a_dst[i * H + hd];
  int j0 = rowptr[i], jend = rowptr[i + 1];
  int deg = jend - j0;

  float denom = 0.f, accx = 0.f, accy = 0.f;
  for (int b0 = 0; b0 < deg; b0 += 64) {
    int li = j0 + b0 + lane;
    if (li > jend - 1) li = jend - 1;
    int sIdx = srcs[li];
    int blkn = deg - b0;
    if (blkn > 64) blkn = 64;
    for (int r0 = 0; r0 < blkn; r0 += 16) {
      int sv[8];
      float asv[8];
      float2 hv[8];
#pragma unroll
      for (int u = 0; u < 8; ++u) sv[u] = __shfl(sIdx, r0 + 2 * u + half);
#pragma unroll
      for (int u = 0; u < 8; ++u) asv[u] = a_src[sv[u] * H + hd];
#pragma unroll
      for (int u = 0; u < 8; ++u)
        hv[u] = *(const float2*)&h[sv[u] * 64 + 2 * p];
#pragma unroll
      for (int u = 0; u < 8; ++u) {
        int r = r0 + 2 * u + half;
        float ll = asv[u] + ad;
        ll = (ll > 0.f) ? ll : 0.2f * ll;
        float ww = __expf(ll);
        ww = (r < blkn) ? ww : 0.f;
        denom += ww;
        accx = fmaf(ww, hv[u].x, accx);
        accy = fmaf(ww, hv[u].y, accy);
      }
    }
  }
  // combine halves (each processed half the edges)
  denom += __shfl_xor(denom, 32);
  accx += __shfl_xor(accx, 32);
  accy += __shfl_xor(accy, 32);
  // self loop (added once per lane, post-combine)
  {
    float l = a_src[i * H + hd] + ad;
    l = (l > 0.f) ? l : 0.2f * l;
    float w = __expf(l);
    float2 hs = *(const float2*)&h[i * 64 + 2 * p];
    denom += w;
    accx = fmaf(w, hs.x, accx);
    accy = fmaf(w, hs.y, accy);
  }
  float inv = 1.f / denom;
  float ox = accx * inv + bias[2 * p];
  float oy = accy * inv + bias[2 * p + 1];
  if (RELU) {
    ox = fmaxf(ox, 0.f);
    oy = fmaxf(oy, 0.f);
  }
  if (HN == 0) {
    if (half == 0) *(float2*)&out[i * 64 + 2 * p] = make_float2(ox, oy);
    return;
  }
  // fused next GEMM: o (identical in both halves) @ Wn
  float a2x = 0.f, a2y = 0.f;
  const float2* ws2 = (const float2*)ws;
#pragma unroll
  for (int k = 0; k < 64; ++k) {
    float ok = __shfl((k & 1) ? oy : ox, k >> 1);
    float2 wv = ws2[k * 32 + p];
    a2x = fmaf(ok, wv.x, a2x);
    a2y = fmaf(ok, wv.y, a2y);
  }
  if (half == 0) *(float2*)&out[i * 64 + 2 * p] = make_float2(a2x, a2y);
  float ts = a2x * asn[2 * p] + a2y * asn[2 * p + 1];
  float td = a2x * adn[2 * p] + a2y * adn[2 * p + 1];
  const int gsp = (HN == 8) ? 4 : 32;  // channel-pairs per next-head
#pragma unroll
  for (int off = 1; off < gsp; off <<= 1) {
    ts += __shfl_xor(ts, off);
    td += __shfl_xor(td, off);
  }
  if (half == 0 && (p & (gsp - 1)) == 0) {
    int hdn = p / gsp;
    a_src_n[i * HN + hdn] = ts;
    a_dst_n[i * HN + hdn] = td;
  }
}

// ---------------- pooling + readout ----------------

__global__ __launch_bounds__(256) void pool_kernel(const float* __restrict__ x,
                                                   const int* __restrict__ batch,
                                                   float* __restrict__ g_sum,
                                                   float* __restrict__ cnt) {
  int wid = (blockIdx.x * 256 + threadIdx.x) >> 6;
  int c = threadIdx.x & 63;
  int n0 = wid * 32;
  if (n0 >= NN) return;
  int nend = n0 + 32 < NN ? n0 + 32 : NN;
  int bi = n0 + (c & 31);
  if (bi > NN - 1) bi = NN - 1;
  int bl = batch[bi];  // one load covers the wave's 32 nodes
  int cur_b = __shfl(bl, 0);
  float acc = 0.f, cacc = 0.f;
  for (int n = n0; n < nend; ++n) {
    int b = __shfl(bl, n - n0);
    if (b != cur_b) {
      atomicAdd(&g_sum[cur_b * 64 + c], acc);
      if (c == 0) atomicAdd(&cnt[cur_b], cacc);
      acc = 0.f;
      cacc = 0.f;
      cur_b = b;
    }
    acc += x[n * 64 + c];
    cacc += 1.f;
  }
  atomicAdd(&g_sum[cur_b * 64 + c], acc);
  if (c == 0) atomicAdd(&cnt[cur_b], cacc);
}

__global__ __launch_bounds__(64) void readout_kernel(
    const float* __restrict__ g_sum, const float* __restrict__ cnt,
    const float* __restrict__ Wm1, const float* __restrict__ bm1,
    const float* __restrict__ Wm2, const float* __restrict__ bm2,
    float* __restrict__ out) {
  int g = blockIdx.x;
  int t = threadIdx.x;
  float cv = fmaxf(cnt[g], 1.f);
  float gv = g_sum[g * 64 + t] / cv;
  float acc = 0.f;
#pragma unroll
  for (int k = 0; k < 64; ++k) {
    float bk = __shfl(gv, k);
    if (t < 32) acc += bk * Wm1[k * 32 + t];
  }
  float m = 0.f;
  if (t < 32) {
    float hid = fmaxf(acc + bm1[t], 0.f);
    m = hid * Wm2[t];
  }
  for (int off = 32; off >= 1; off >>= 1) m += __shfl_xor(m, off);
  if (t == 0) out[g] = m + bm2[0];
}

// ---------------- launch ----------------

extern "C" void kernel_launch(void* const* d_in, const int* in_sizes, int n_in,
                              void* d_out, int out_size, void* d_ws, size_t ws_size,
                              hipStream_t stream) {
  const float* x0       = (const float*)d_in[0];
  const int*   edge_idx = (const int*)d_in[1];
  const int*   batch    = (const int*)d_in[3];
  const int*   dis_idx  = (const int*)d_in[6];
  const float* W1  = (const float*)d_in[7];
  const float* as1 = (const float*)d_in[8];
  const float* ad1 = (const float*)d_in[9];
  const float* b1  = (const float*)d_in[10];
  const float* W2  = (const float*)d_in[11];
  const float* as2 = (const float*)d_in[12];
  const float* ad2 = (const float*)d_in[13];
  const float* b2  = (const float*)d_in[14];
  const float* Wm1 = (const float*)d_in[19];
  const float* bm1 = (const float*)d_in[20];
  const float* Wm2 = (const float*)d_in[21];
  const float* bm2 = (const float*)d_in[22];
  float* out = (float*)d_out;

  char* ws = (char*)d_ws;
  size_t off = 0;
  auto alloc = [&](size_t bytes) {
    void* p = ws + off;
    off += (bytes + 255) & ~(size_t)255;
    return p;
  };
  float* hA    = (float*)alloc(NN * 64 * 4);
  float* hB    = (float*)alloc(NN * 64 * 4);
  float* xF    = (float*)alloc(NN * 64 * 4);
  float* asA   = (float*)alloc(NN * 8 * 4);
  float* adA   = (float*)alloc(NN * 8 * 4);
  float* asB   = (float*)alloc(NN * 8 * 4);
  float* adB   = (float*)alloc(NN * 8 * 4);
  int* rp_d    = (int*)alloc((NN + 1) * 4);
  int* s_d     = (int*)alloc(NE * 4);
  int* rp_e    = (int*)alloc((NN + 1) * 4);
  int* s_e     = (int*)alloc(NE * 4);
  // contiguous zero region: cnt_d, cur_d, cnt_e, cur_e, g_sum, gcnt
  char* zero0  = ws + off;
  int* cnt_d   = (int*)alloc(NN * 4);
  int* cur_d   = (int*)alloc(NN * 4);
  int* cnt_e   = (int*)alloc(NN * 4);
  int* cur_e   = (int*)alloc(NN * 4);
  float* g_sum = (float*)alloc(NG * 64 * 4);
  float* gcnt  = (float*)alloc(NG * 4);
  size_t zbytes = (size_t)((char*)(ws + off) - zero0);

  const size_t SH = 64 * 64 * sizeof(float);
  const int NB = NN / 4;  // 5000

  hipMemsetAsync(zero0, 0, zbytes, stream);
  hist_both_kernel<<<2 * EB, 256, 0, stream>>>(dis_idx + NE, edge_idx + NE, cnt_d, cnt_e);
  scan_both_kernel<<<2, 1024, 0, stream>>>(cnt_d, rp_d, cnt_e, rp_e);
  scatter_both_kernel<<<2 * EB, 256, 0, stream>>>(dis_idx, edge_idx, rp_d, rp_e,
                                                  cur_d, cur_e, s_d, s_e);

  // first conv1 GEMM + attention sums (H=8)
  gemm_attn_kernel<<<NB, 256, 0, stream>>>(x0, W1, as1, ad1, hA, asA, adA);

  // 12 convs; even = conv1 (H=8, relu, fuse W2), odd = conv2 (H=1, fuse W1)
  for (int k = 0; k < 12; ++k) {
    const int* rp = (((k >> 1) & 1) == 0) ? rp_d : rp_e;
    const int* ss = (((k >> 1) & 1) == 0) ? s_d : s_e;
    if ((k & 1) == 0) {
      agg_fused_kernel<8, true, 1><<<NB, 256, SH, stream>>>(
          hA, asA, adA, rp, ss, b1, hB, W2, as2, ad2, asB, adB);
    } else if (k < 11) {
      agg_fused_kernel<1, false, 8><<<NB, 256, SH, stream>>>(
          hB, asB, adB, rp, ss, b2, hA, W1, as1, ad1, asA, adA);
    } else {
      agg_fused_kernel<1, false, 0><<<NB, 256, 0, stream>>>(
          hB, asB, adB, rp, ss, b2, xF, nullptr, nullptr, nullptr,
          nullptr, nullptr);
    }
  }

  // global mean pool + readout
  pool_kernel<<<(NN / 32 + 3) / 4, 256, 0, stream>>>(xF, batch, g_sum, gcnt);
  readout_kernel<<<NG, 64, 0, stream>>>(g_sum, gcnt, Wm1, bm1, Wm2, bm2, out);
}

// Round 6
// 523.294 us; speedup vs baseline: 1.0071x; 1.0071x over previous
//
#include <hip/hip_runtime.h>
#include <hip/hip_fp16.h>

#define NN 20000
#define NE 320000
#define NG 256
#define EB 1250  // NE / 256 exactly

// ---------------- CSR build ----------------

// grid = 2*EB: first EB blocks histogram dis dst, rest edge dst.
__global__ __launch_bounds__(256) void hist_both_kernel(
    const int* __restrict__ dis_dst, const int* __restrict__ edge_dst,
    int* __restrict__ cnt_d, int* __restrict__ cnt_e) {
  int b = blockIdx.x;
  if (b < EB) {
    int e = b * 256 + threadIdx.x;
    atomicAdd(&cnt_d[dis_dst[e]], 1);
  } else {
    int e = (b - EB) * 256 + threadIdx.x;
    atomicAdd(&cnt_e[edge_dst[e]], 1);
  }
}

// grid = 2: block 0 scans cnt_d -> rp_d, block 1 scans cnt_e -> rp_e.
__global__ __launch_bounds__(1024) void scan_both_kernel(
    const int* __restrict__ cnt_d, int* __restrict__ rp_d,
    const int* __restrict__ cnt_e, int* __restrict__ rp_e) {
  const int* counts = (blockIdx.x == 0) ? cnt_d : cnt_e;
  int* rowptr = (blockIdx.x == 0) ? rp_d : rp_e;
  __shared__ int wsum[16];
  __shared__ int carry_s;
  int t = threadIdx.x;
  int lane = t & 63;
  int w = t >> 6;
  if (t == 0) carry_s = 0;
  __syncthreads();
  for (int base = 0; base < NN; base += 1024) {
    int v = (base + t < NN) ? counts[base + t] : 0;
    int incl = v;
#pragma unroll
    for (int off = 1; off < 64; off <<= 1) {
      int g = __shfl_up(incl, off);
      if (lane >= off) incl += g;
    }
    if (lane == 63) wsum[w] = incl;
    __syncthreads();
    if (w == 0 && lane < 16) {
      int s = wsum[lane];
#pragma unroll
      for (int off = 1; off < 16; off <<= 1) {
        int g = __shfl_up(s, off);
        if (lane >= off) s += g;
      }
      wsum[lane] = s;
    }
    __syncthreads();
    int woff = (w > 0) ? wsum[w - 1] : 0;
    int carry = carry_s;
    int tot = carry + woff + incl;
    if (base + t < NN) rowptr[base + t] = tot - v;  // exclusive
    __syncthreads();
    if (t == 1023) carry_s = tot;
    __syncthreads();
  }
  if (t == 0) rowptr[NN] = carry_s;
}

// grid = 2*EB, mirrors hist_both.
__global__ __launch_bounds__(256) void scatter_both_kernel(
    const int* __restrict__ dis_idx, const int* __restrict__ edge_idx,
    const int* __restrict__ rp_d, const int* __restrict__ rp_e,
    int* __restrict__ cur_d, int* __restrict__ cur_e,
    int* __restrict__ s_d, int* __restrict__ s_e) {
  int b = blockIdx.x;
  if (b < EB) {
    int e = b * 256 + threadIdx.x;
    int d = dis_idx[NE + e];
    int pos = rp_d[d] + atomicAdd(&cur_d[d], 1);
    s_d[pos] = dis_idx[e];
  } else {
    int e = (b - EB) * 256 + threadIdx.x;
    int d = edge_idx[NE + e];
    int pos = rp_e[d] + atomicAdd(&cur_e[d], 1);
    s_e[pos] = edge_idx[e];
  }
}

// ---------------- first GEMM + attention sums ----------------
// h written fp16 (L2-resident, half gather traffic); attn sums from fp32 acc.

__global__ __launch_bounds__(256) void gemm_attn_kernel(
    const float* __restrict__ x, const float* __restrict__ W,
    const float* __restrict__ att_src, const float* __restrict__ att_dst,
    __half* __restrict__ h, float* __restrict__ a_src, float* __restrict__ a_dst) {
  __shared__ float xs[4][64];
  __shared__ float ws[64 * 64];
  int t = threadIdx.x;
  int lr = t >> 6;
  int c = t & 63;
  int n = blockIdx.x * 4 + lr;
  const float4* W4 = (const float4*)W;
  float4* ws4 = (float4*)ws;
  for (int k = t; k < 1024; k += 256) ws4[k] = W4[k];
  xs[lr][c] = x[n * 64 + c];
  __syncthreads();
  float acc = 0.f;
#pragma unroll
  for (int k = 0; k < 64; ++k) acc = fmaf(xs[lr][k], ws[k * 64 + c], acc);
  h[n * 64 + c] = __float2half(acc);
  float ts = acc * att_src[c];
  float td = acc * att_dst[c];
#pragma unroll
  for (int off = 1; off < 8; off <<= 1) {
    ts += __shfl_xor(ts, off);
    td += __shfl_xor(td, off);
  }
  if ((c & 7) == 0) {
    a_src[n * 8 + (c >> 3)] = ts;
    a_dst[n * 8 + (c >> 3)] = td;
  }
}

// ---------------- fused agg (+ optional next-conv GEMM/attn) ----------------
// One wave per dst node. lane = (half, p): channels {2p, 2p+1}; half 0 even
// edges, half 1 odd edges. h gathered as __half2 (4B/lane, 128B/edge, L2-hit).
// Accumulation fp32. HN!=0: fused next GEMM writes fp16 h + fp32 attn sums.
template <int H, bool RELU, int HN>
__global__ __launch_bounds__(256) void agg_fused_kernel(
    const __half* __restrict__ h, const float* __restrict__ a_src,
    const float* __restrict__ a_dst, const int* __restrict__ rowptr,
    const int* __restrict__ srcs, const float* __restrict__ bias,
    __half* __restrict__ out_h, float* __restrict__ out_f,
    const float* __restrict__ Wn, const float* __restrict__ asn,
    const float* __restrict__ adn, float* __restrict__ a_src_n,
    float* __restrict__ a_dst_n) {
  extern __shared__ float ws[];
  int t = threadIdx.x;
  int i = blockIdx.x * 4 + (t >> 6);
  int lane = t & 63;
  int half = lane >> 5;
  int p = lane & 31;  // channel pair; channels 2p, 2p+1 (same head always)
  if (HN != 0) {
    const float4* W4 = (const float4*)Wn;
    float4* ws4 = (float4*)ws;
    for (int k = t; k < 1024; k += 256) ws4[k] = W4[k];
    __syncthreads();
  }
  const int hd = (H == 8) ? (p >> 2) : 0;
  float ad = a_dst[i * H + hd];
  int j0 = rowptr[i], jend = rowptr[i + 1];
  int deg = jend - j0;

  float denom = 0.f, accx = 0.f, accy = 0.f;
  for (int b0 = 0; b0 < deg; b0 += 64) {
    int li = j0 + b0 + lane;
    if (li > jend - 1) li = jend - 1;
    int sIdx = srcs[li];
    int blkn = deg - b0;
    if (blkn > 64) blkn = 64;
    for (int r0 = 0; r0 < blkn; r0 += 16) {
      int sv[8];
      float asv[8];
      __half2 hv[8];
#pragma unroll
      for (int u = 0; u < 8; ++u) sv[u] = __shfl(sIdx, r0 + 2 * u + half);
#pragma unroll
      for (int u = 0; u < 8; ++u) asv[u] = a_src[sv[u] * H + hd];
#pragma unroll
      for (int u = 0; u < 8; ++u)
        hv[u] = *(const __half2*)&h[sv[u] * 64 + 2 * p];
#pragma unroll
      for (int u = 0; u < 8; ++u) {
        int r = r0 + 2 * u + half;
        float ll = asv[u] + ad;
        ll = (ll > 0.f) ? ll : 0.2f * ll;
        float ww = __expf(ll);
        ww = (r < blkn) ? ww : 0.f;
        float2 hf = __half22float2(hv[u]);
        denom += ww;
        accx = fmaf(ww, hf.x, accx);
        accy = fmaf(ww, hf.y, accy);
      }
    }
  }
  // combine halves (each processed half the edges)
  denom += __shfl_xor(denom, 32);
  accx += __shfl_xor(accx, 32);
  accy += __shfl_xor(accy, 32);
  // self loop (added once per lane, post-combine)
  {
    float l = a_src[i * H + hd] + ad;
    l = (l > 0.f) ? l : 0.2f * l;
    float w = __expf(l);
    float2 hs = __half22float2(*(const __half2*)&h[i * 64 + 2 * p]);
    denom += w;
    accx = fmaf(w, hs.x, accx);
    accy = fmaf(w, hs.y, accy);
  }
  float inv = 1.f / denom;
  float ox = accx * inv + bias[2 * p];
  float oy = accy * inv + bias[2 * p + 1];
  if (RELU) {
    ox = fmaxf(ox, 0.f);
    oy = fmaxf(oy, 0.f);
  }
  if (HN == 0) {
    if (half == 0) *(float2*)&out_f[i * 64 + 2 * p] = make_float2(ox, oy);
    return;
  }
  // fused next GEMM: o (identical in both halves) @ Wn
  float a2x = 0.f, a2y = 0.f;
  const float2* ws2 = (const float2*)ws;
#pragma unroll
  for (int k = 0; k < 64; ++k) {
    float ok = __shfl((k & 1) ? oy : ox, k >> 1);
    float2 wv = ws2[k * 32 + p];
    a2x = fmaf(ok, wv.x, a2x);
    a2y = fmaf(ok, wv.y, a2y);
  }
  if (half == 0) *(__half2*)&out_h[i * 64 + 2 * p] = __floats2half2_rn(a2x, a2y);
  float ts = a2x * asn[2 * p] + a2y * asn[2 * p + 1];
  float td = a2x * adn[2 * p] + a2y * adn[2 * p + 1];
  const int gsp = (HN == 8) ? 4 : 32;  // channel-pairs per next-head
#pragma unroll
  for (int off = 1; off < gsp; off <<= 1) {
    ts += __shfl_xor(ts, off);
    td += __shfl_xor(td, off);
  }
  if (half == 0 && (p & (gsp - 1)) == 0) {
    int hdn = p / gsp;
    a_src_n[i * HN + hdn] = ts;
    a_dst_n[i * HN + hdn] = td;
  }
}

// ---------------- pooling + readout ----------------

__global__ __launch_bounds__(256) void pool_kernel(const float* __restrict__ x,
                                                   const int* __restrict__ batch,
                                                   float* __restrict__ g_sum,
                                                   float* __restrict__ cnt) {
  int wid = (blockIdx.x * 256 + threadIdx.x) >> 6;
  int c = threadIdx.x & 63;
  int n0 = wid * 32;
  if (n0 >= NN) return;
  int nend = n0 + 32 < NN ? n0 + 32 : NN;
  int bi = n0 + (c & 31);
  if (bi > NN - 1) bi = NN - 1;
  int bl = batch[bi];  // one load covers the wave's 32 nodes
  int cur_b = __shfl(bl, 0);
  float acc = 0.f, cacc = 0.f;
  for (int n = n0; n < nend; ++n) {
    int b = __shfl(bl, n - n0);
    if (b != cur_b) {
      atomicAdd(&g_sum[cur_b * 64 + c], acc);
      if (c == 0) atomicAdd(&cnt[cur_b], cacc);
      acc = 0.f;
      cacc = 0.f;
      cur_b = b;
    }
    acc += x[n * 64 + c];
    cacc += 1.f;
  }
  atomicAdd(&g_sum[cur_b * 64 + c], acc);
  if (c == 0) atomicAdd(&cnt[cur_b], cacc);
}

__global__ __launch_bounds__(64) void readout_kernel(
    const float* __restrict__ g_sum, const float* __restrict__ cnt,
    const float* __restrict__ Wm1, const float* __restrict__ bm1,
    const float* __restrict__ Wm2, const float* __restrict__ bm2,
    float* __restrict__ out) {
  int g = blockIdx.x;
  int t = threadIdx.x;
  float cv = fmaxf(cnt[g], 1.f);
  float gv = g_sum[g * 64 + t] / cv;
  float acc = 0.f;
#pragma unroll
  for (int k = 0; k < 64; ++k) {
    float bk = __shfl(gv, k);
    if (t < 32) acc += bk * Wm1[k * 32 + t];
  }
  float m = 0.f;
  if (t < 32) {
    float hid = fmaxf(acc + bm1[t], 0.f);
    m = hid * Wm2[t];
  }
  for (int off = 32; off >= 1; off >>= 1) m += __shfl_xor(m, off);
  if (t == 0) out[g] = m + bm2[0];
}

// ---------------- launch ----------------

extern "C" void kernel_launch(void* const* d_in, const int* in_sizes, int n_in,
                              void* d_out, int out_size, void* d_ws, size_t ws_size,
                              hipStream_t stream) {
  const float* x0       = (const float*)d_in[0];
  const int*   edge_idx = (const int*)d_in[1];
  const int*   batch    = (const int*)d_in[3];
  const int*   dis_idx  = (const int*)d_in[6];
  const float* W1  = (const float*)d_in[7];
  const float* as1 = (const float*)d_in[8];
  const float* ad1 = (const float*)d_in[9];
  const float* b1  = (const float*)d_in[10];
  const float* W2  = (const float*)d_in[11];
  const float* as2 = (const float*)d_in[12];
  const float* ad2 = (const float*)d_in[13];
  const float* b2  = (const float*)d_in[14];
  const float* Wm1 = (const float*)d_in[19];
  const float* bm1 = (const float*)d_in[20];
  const float* Wm2 = (const float*)d_in[21];
  const float* bm2 = (const float*)d_in[22];
  float* out = (float*)d_out;

  char* ws = (char*)d_ws;
  size_t off = 0;
  auto alloc = [&](size_t bytes) {
    void* p = ws + off;
    off += (bytes + 255) & ~(size_t)255;
    return p;
  };
  __half* hA   = (__half*)alloc(NN * 64 * 2);
  __half* hB   = (__half*)alloc(NN * 64 * 2);
  float* xF    = (float*)alloc(NN * 64 * 4);
  float* asA   = (float*)alloc(NN * 8 * 4);
  float* adA   = (float*)alloc(NN * 8 * 4);
  float* asB   = (float*)alloc(NN * 8 * 4);
  float* adB   = (float*)alloc(NN * 8 * 4);
  int* rp_d    = (int*)alloc((NN + 1) * 4);
  int* s_d     = (int*)alloc(NE * 4);
  int* rp_e    = (int*)alloc((NN + 1) * 4);
  int* s_e     = (int*)alloc(NE * 4);
  // contiguous zero region: cnt_d, cur_d, cnt_e, cur_e, g_sum, gcnt
  char* zero0  = ws + off;
  int* cnt_d   = (int*)alloc(NN * 4);
  int* cur_d   = (int*)alloc(NN * 4);
  int* cnt_e   = (int*)alloc(NN * 4);
  int* cur_e   = (int*)alloc(NN * 4);
  float* g_sum = (float*)alloc(NG * 64 * 4);
  float* gcnt  = (float*)alloc(NG * 4);
  size_t zbytes = (size_t)((char*)(ws + off) - zero0);

  const size_t SH = 64 * 64 * sizeof(float);
  const int NB = NN / 4;  // 5000

  hipMemsetAsync(zero0, 0, zbytes, stream);
  hist_both_kernel<<<2 * EB, 256, 0, stream>>>(dis_idx + NE, edge_idx + NE, cnt_d, cnt_e);
  scan_both_kernel<<<2, 1024, 0, stream>>>(cnt_d, rp_d, cnt_e, rp_e);
  scatter_both_kernel<<<2 * EB, 256, 0, stream>>>(dis_idx, edge_idx, rp_d, rp_e,
                                                  cur_d, cur_e, s_d, s_e);

  // first conv1 GEMM + attention sums (H=8)
  gemm_attn_kernel<<<NB, 256, 0, stream>>>(x0, W1, as1, ad1, hA, asA, adA);

  // 12 convs; even = conv1 (H=8, relu, fuse W2), odd = conv2 (H=1, fuse W1)
  for (int k = 0; k < 12; ++k) {
    const int* rp = (((k >> 1) & 1) == 0) ? rp_d : rp_e;
    const int* ss = (((k >> 1) & 1) == 0) ? s_d : s_e;
    if ((k & 1) == 0) {
      agg_fused_kernel<8, true, 1><<<NB, 256, SH, stream>>>(
          hA, asA, adA, rp, ss, b1, hB, nullptr, W2, as2, ad2, asB, adB);
    } else if (k < 11) {
      agg_fused_kernel<1, false, 8><<<NB, 256, SH, stream>>>(
          hB, asB, adB, rp, ss, b2, hA, nullptr, W1, as1, ad1, asA, adA);
    } else {
      agg_fused_kernel<1, false, 0><<<NB, 256, 0, stream>>>(
          hB, asB, adB, rp, ss, b2, nullptr, xF, nullptr, nullptr, nullptr,
          nullptr, nullptr);
    }
  }

  // global mean pool + readout
  pool_kernel<<<(NN / 32 + 3) / 4, 256, 0, stream>>>(xF, batch, g_sum, gcnt);
  readout_kernel<<<NG, 64, 0, stream>>>(g_sum, gcnt, Wm1, bm1, Wm2, bm2, out);
}